// Round 19
// baseline (303.642 us; speedup 1.0000x reference)
//
#include <hip/hip_runtime.h>
#include <stdint.h>

typedef __bf16 bf16_t;
typedef bf16_t bf16x2 __attribute__((ext_vector_type(2)));
typedef bf16_t bf16x8 __attribute__((ext_vector_type(8)));
typedef float f32x4 __attribute__((ext_vector_type(4)));
typedef float f32x16 __attribute__((ext_vector_type(16)));
typedef unsigned short u16;
typedef u16 u16x8 __attribute__((ext_vector_type(8)));
typedef u16 u16x4 __attribute__((ext_vector_type(4)));
typedef unsigned int u32;
typedef u32 u32x2 __attribute__((ext_vector_type(2)));
typedef u32 u32x4v __attribute__((ext_vector_type(4)));

// f32 -> bf16 RTNE (inputs finite; NaN path not needed)
__device__ __forceinline__ u16 f2b(float f) {
  uint32_t u = __builtin_bit_cast(uint32_t, f);
  u += 0x7fffu + ((u >> 16) & 1u);
  return (u16)(u >> 16);
}

// pack two f32 -> one u32 of 2 bf16 via compiler casts (no inline asm)
__device__ __forceinline__ u32 pkbf(float lo, float hi) {
  bf16x2 t = {(__bf16)lo, (__bf16)hi};
  return __builtin_bit_cast(u32, t);
}

__device__ __forceinline__ void gl_lds16(const void* g, void* l) {
  __builtin_amdgcn_global_load_lds(
      (const __attribute__((address_space(1))) uint32_t*)(uintptr_t)g,
      (__attribute__((address_space(3))) uint32_t*)(uintptr_t)l, 16, 0, 0);
}

// ---------------- fused cast: x + 4 weight matrices in ONE launch ----------------
__global__ void cast5_bf16(const float* __restrict__ x, const float* __restrict__ a,
                           const float* __restrict__ b, const float* __restrict__ c,
                           const float* __restrict__ d,
                           u16* __restrict__ xb, u16* __restrict__ wb) {
  const int y = blockIdx.y;
  const float* srcs[5] = {x, a, b, c, d};
  const float* src = srcs[y];
  u16* dp = (y == 0) ? xb : wb + (size_t)(y - 1) * 1024 * 1024;
  const int n8 = (y == 0) ? 1048576 : 131072;
  int i = blockIdx.x * blockDim.x + threadIdx.x;
  int stride = gridDim.x * blockDim.x;
  for (; i < n8; i += stride) {
    float4 p = ((const float4*)src)[2 * i];
    float4 q = ((const float4*)src)[2 * i + 1];
    u16x8 o;
    o[0] = f2b(p.x); o[1] = f2b(p.y); o[2] = f2b(p.z); o[3] = f2b(p.w);
    o[4] = f2b(q.x); o[5] = f2b(q.y); o[6] = f2b(q.z); o[7] = f2b(q.w);
    ((u16x8*)dp)[i] = o;
  }
}

// ---------------- merged QKV GEMM, BK=64, XOR-swizzled LDS, XCD 1D grid -----------
__global__ __launch_bounds__(256, 2)
void gemm_qkv(const u16* __restrict__ A, const u16* __restrict__ W3,
              u16* __restrict__ qb, u16* __restrict__ kb2, u16* __restrict__ vtb,
              float qscale) {
  __shared__ u16 As[128 * 64];
  __shared__ u16 Bs[128 * 64];
  const int tid  = threadIdx.x;
  const int lane = tid & 63;
  const int w    = tid >> 6;
  const int wm   = w >> 1, wn = w & 1;
  const int g    = lane >> 4, c = lane & 15;
  const int id   = blockIdx.x;
  const int wg   = (id & 7) * 192 + (id >> 3);   // XCD-contiguous remap (1536%8==0)
  const int which = wg >> 9;
  const int rem   = wg & 511;
  const int n0    = (rem & 7) * 128;
  const int m0    = (rem >> 3) * 128;
  const u16* Wt = W3 + (size_t)which * 1024 * 1024;

  f32x4 acc[4][4] = {};

  const int srow = tid >> 3;
  const int sslx = (tid & 7) ^ (srow & 7);
  const u16* gA = A  + (size_t)(m0 + srow) * 1024 + sslx * 8;
  const u16* gB = Wt + (size_t)(n0 + srow) * 1024 + sslx * 8;
  char* lA = (char*)As + w * 1024;
  char* lB = (char*)Bs + w * 1024;
  const int cx = c & 7;                 // read-side xor (row&7 == c&7)

#pragma unroll 1
  for (int kt = 0; kt < 1024; kt += 64) {
    __syncthreads();
#pragma unroll
    for (int j = 0; j < 4; ++j) {
      gl_lds16(gA + kt + (size_t)j * 32 * 1024, lA + j * 4096);
      gl_lds16(gB + kt + (size_t)j * 32 * 1024, lB + j * 4096);
    }
    __syncthreads();
#pragma unroll
    for (int ks = 0; ks < 2; ++ks) {
      bf16x8 af[4], bfr[4];
#pragma unroll
      for (int mi = 0; mi < 4; ++mi)
        af[mi] = *(const bf16x8*)((const char*)As + (wm * 64 + mi * 16 + c) * 128 +
                                  (((ks * 4 + g) ^ cx) << 4));
#pragma unroll
      for (int ni = 0; ni < 4; ++ni)
        bfr[ni] = *(const bf16x8*)((const char*)Bs + (wn * 64 + ni * 16 + c) * 128 +
                                   (((ks * 4 + g) ^ cx) << 4));
#pragma unroll
      for (int mi = 0; mi < 4; ++mi)
#pragma unroll
        for (int ni = 0; ni < 4; ++ni)
          acc[mi][ni] = __builtin_amdgcn_mfma_f32_16x16x32_bf16(af[mi], bfr[ni], acc[mi][ni], 0, 0, 0);
    }
  }

  const int rowb = m0 + wm * 64;
  const int colb = n0 + wn * 64;

  if (which <= 1) {
    u16* outb = (which == 0) ? qb : kb2;
    const float scale = (which == 0) ? qscale : 1.0f;
#pragma unroll
    for (int mi = 0; mi < 4; ++mi)
#pragma unroll
      for (int ni = 0; ni < 4; ++ni) {
        size_t base = (size_t)(rowb + mi * 16 + g * 4) * 1024 + (colb + ni * 16 + c);
#pragma unroll
        for (int r = 0; r < 4; ++r)
          outb[base + (size_t)r * 1024] = f2b(acc[mi][ni][r] * scale);
      }
  } else {
#pragma unroll
    for (int mi = 0; mi < 4; ++mi) {
      int row = rowb + mi * 16 + g * 4;
      int bb = row >> 11, tl = row & 2047;
#pragma unroll
      for (int ni = 0; ni < 4; ++ni) {
        int col = colb + ni * 16 + c;
        u16x4 pk;
#pragma unroll
        for (int r = 0; r < 4; ++r) pk[r] = f2b(acc[mi][ni][r]);
        *(u16x4*)(vtb + ((size_t)(bb * 1024 + col)) * 2048 + tl) = pk;
      }
    }
  }
}

// ---------------- output-projection GEMM, BK=64, swizzled: f32 out + bias ---------
__global__ __launch_bounds__(256, 2)
void gemm_out(const u16* __restrict__ A, const u16* __restrict__ Wt,
              float* __restrict__ outf, const float* __restrict__ bias) {
  __shared__ u16 As[128 * 64];
  __shared__ u16 Bs[128 * 64];
  const int tid  = threadIdx.x;
  const int lane = tid & 63;
  const int w    = tid >> 6;
  const int wm   = w >> 1, wn = w & 1;
  const int g    = lane >> 4, c = lane & 15;
  const int id   = blockIdx.x;
  const int wg   = (id & 7) * 64 + (id >> 3);    // 512 blocks, XCD-contiguous
  const int n0   = (wg & 7) * 128;
  const int m0   = (wg >> 3) * 128;

  f32x4 acc[4][4] = {};

  const int srow = tid >> 3;
  const int sslx = (tid & 7) ^ (srow & 7);
  const u16* gA = A  + (size_t)(m0 + srow) * 1024 + sslx * 8;
  const u16* gB = Wt + (size_t)(n0 + srow) * 1024 + sslx * 8;
  char* lA = (char*)As + w * 1024;
  char* lB = (char*)Bs + w * 1024;
  const int cx = c & 7;

#pragma unroll 1
  for (int kt = 0; kt < 1024; kt += 64) {
    __syncthreads();
#pragma unroll
    for (int j = 0; j < 4; ++j) {
      gl_lds16(gA + kt + (size_t)j * 32 * 1024, lA + j * 4096);
      gl_lds16(gB + kt + (size_t)j * 32 * 1024, lB + j * 4096);
    }
    __syncthreads();
#pragma unroll
    for (int ks = 0; ks < 2; ++ks) {
      bf16x8 af[4], bfr[4];
#pragma unroll
      for (int mi = 0; mi < 4; ++mi)
        af[mi] = *(const bf16x8*)((const char*)As + (wm * 64 + mi * 16 + c) * 128 +
                                  (((ks * 4 + g) ^ cx) << 4));
#pragma unroll
      for (int ni = 0; ni < 4; ++ni)
        bfr[ni] = *(const bf16x8*)((const char*)Bs + (wn * 64 + ni * 16 + c) * 128 +
                                   (((ks * 4 + g) ^ cx) << 4));
#pragma unroll
      for (int mi = 0; mi < 4; ++mi)
#pragma unroll
        for (int ni = 0; ni < 4; ++ni)
          acc[mi][ni] = __builtin_amdgcn_mfma_f32_16x16x32_bf16(af[mi], bfr[ni], acc[mi][ni], 0, 0, 0);
    }
  }

  const int rowb = m0 + wm * 64;
  const int colb = n0 + wn * 64;
#pragma unroll
  for (int ni = 0; ni < 4; ++ni) {
    int col = colb + ni * 16 + c;
    float bv = bias[col];
#pragma unroll
    for (int mi = 0; mi < 4; ++mi) {
      size_t base = (size_t)(rowb + mi * 16 + g * 4) * 1024 + col;
#pragma unroll
      for (int r = 0; r < 4; ++r)
        outf[base + (size_t)r * 1024] = acc[mi][ni][r] + bv;
    }
  }
}

// ---------------- fused attention v15: gl_lds staging + 128-key tiles + setprio ----
// v14 (passed, 81us) with two riders:
//  1) 128-key tiles: 8 gl_lds per step into [K0|K1|V0|V1] (32 KB), 16 steps ->
//     32 barriers (was 64). Safe now: gl_lds holds ZERO prefetch registers
//     (v13's spill came from 32 uint4 prefetch regs; that path is gone).
//     Keys ascend -> bit-identical accumulation.
//  2) T5 s_setprio(1) around MFMA clusters: independent blocks' waves co-reside
//     per SIMD at different phases (attn regime where m191 measured +4-7%).
//     Pure scheduler hint.
__global__ __launch_bounds__(256, 2)
void attn_fused(const u16* __restrict__ qb, const u16* __restrict__ kb,
                const u16* __restrict__ vt, u16* __restrict__ ob) {
  __shared__ u16 KV[4][4096];  // [K0|K1|V0|V1], XOR-swizzled source, linear dest

  const int bh = blockIdx.x;            // 0..63
  const int qt = blockIdx.y;            // 0..7
  const int b  = bh >> 4, h = bh & 15;
  const int tid  = threadIdx.x;
  const int lane = tid & 63;
  const int w    = tid >> 6;
  const int l31  = lane & 31, g32 = lane >> 5;

  // ---- staging: row r = tid>>3 (+32/+64/+96), slot pre-swizzled (tid&7)^(r&7) ----
  const int r  = tid >> 3;
  const int sx = (tid & 7) ^ (r & 7);
  const u16* kgs = kb + (size_t)(b * 2048 + r) * 1024 + h * 64 + sx * 8;
  const u16* vgs = vt + (size_t)(bh * 64 + r) * 2048 + sx * 8;
  char* lK0 = (char*)&KV[0][0] + w * 1024;   // wave-uniform dest; lane stride 16B
  char* lK1 = (char*)&KV[1][0] + w * 1024;
  char* lV0 = (char*)&KV[2][0] + w * 1024;
  char* lV1 = (char*)&KV[3][0] + w * 1024;

  const int qrow0 = b * 2048 + qt * 256 + w * 64;
  bf16x8 qf[2][4];
#pragma unroll
  for (int q2 = 0; q2 < 2; ++q2)
#pragma unroll
    for (int dc = 0; dc < 4; ++dc)
      qf[q2][dc] = *(const bf16x8*)(qb + (size_t)(qrow0 + q2 * 32 + l31) * 1024 +
                                    h * 64 + dc * 16 + g32 * 8);

  f32x16 Oa[2][2] = {};   // [q2][db] : O^T accumulators
  float lp[2] = {0.f, 0.f};

  const int xorv = (l31 & 7) << 4;      // read-side swizzle (row&7)<<4
  const int rowb = l31 * 128;           // row byte offset within 32-row half

#pragma unroll 1
  for (int step = 0; step < 16; ++step) {
    const int s0 = step * 128;
    __syncthreads();                 // A: all waves done READING prev tile (WAR)
    gl_lds16(kgs + (size_t)s0 * 1024,         lK0);
    gl_lds16(kgs + (size_t)(s0 + 32) * 1024,  lK0 + 4096);
    gl_lds16(kgs + (size_t)(s0 + 64) * 1024,  lK1);
    gl_lds16(kgs + (size_t)(s0 + 96) * 1024,  lK1 + 4096);
    gl_lds16(vgs + s0,                        lV0);
    gl_lds16(vgs + s0 + (size_t)32 * 2048,    lV0 + 4096);
    gl_lds16(vgs + s0 + 64,                   lV1);
    gl_lds16(vgs + s0 + 64 + (size_t)32 * 2048, lV1 + 4096);
    __syncthreads();                 // B: drains gl_lds (vmcnt 0) + all waves staged

#pragma unroll
    for (int ksub = 0; ksub < 2; ++ksub) {
      const char* kt  = (const char*)&KV[ksub][0];
      const char* vtl = (const char*)&KV[2 + ksub][0];

#pragma unroll
      for (int kb2 = 0; kb2 < 2; ++kb2) {
        bf16x8 kf[4];
#pragma unroll
        for (int dc = 0; dc < 4; ++dc)
          kf[dc] = *(const bf16x8*)(kt + kb2 * 4096 + rowb + ((dc * 32 + g32 * 16) ^ xorv));
        bf16x8 vf[2][2];
#pragma unroll
        for (int db = 0; db < 2; ++db)
#pragma unroll
          for (int ck = 0; ck < 2; ++ck)
            vf[db][ck] = *(const bf16x8*)(vtl + db * 4096 + rowb +
                                          (((kb2 * 2 + ck) * 32 + g32 * 16) ^ xorv));

#pragma unroll
        for (int q2 = 0; q2 < 2; ++q2) {
          f32x16 S = {};
          __builtin_amdgcn_s_setprio(1);
#pragma unroll
          for (int dc = 0; dc < 4; ++dc)
            S = __builtin_amdgcn_mfma_f32_32x32x16_bf16(kf[dc], qf[q2][dc], S, 0, 0, 0);
          __builtin_amdgcn_s_setprio(0);

          float p[16];
#pragma unroll
          for (int rr = 0; rr < 16; ++rr) p[rr] = __builtin_amdgcn_exp2f(S[rr]);
          float s01 = (p[0] + p[1]) + (p[2] + p[3]);
          float s02 = (p[4] + p[5]) + (p[6] + p[7]);
          float s03 = (p[8] + p[9]) + (p[10] + p[11]);
          float s04 = (p[12] + p[13]) + (p[14] + p[15]);
          lp[q2] += (s01 + s02) + (s03 + s04);

          u32 w0 = pkbf(p[0], p[1]),   w1 = pkbf(p[2], p[3]);
          u32 w2 = pkbf(p[4], p[5]),   w3 = pkbf(p[6], p[7]);
          u32 w4 = pkbf(p[8], p[9]),   w5 = pkbf(p[10], p[11]);
          u32 w6 = pkbf(p[12], p[13]), w7 = pkbf(p[14], p[15]);
          u32x2 sA = __builtin_amdgcn_permlane32_swap(w0, w2, false, false);
          u32x2 sB = __builtin_amdgcn_permlane32_swap(w1, w3, false, false);
          u32x2 sC = __builtin_amdgcn_permlane32_swap(w4, w6, false, false);
          u32x2 sD = __builtin_amdgcn_permlane32_swap(w5, w7, false, false);
          u32x4v q0 = {sA[0], sB[0], sA[1], sB[1]};
          u32x4v q1 = {sC[0], sD[0], sC[1], sD[1]};
          bf16x8 pb0 = __builtin_bit_cast(bf16x8, q0);
          bf16x8 pb1 = __builtin_bit_cast(bf16x8, q1);

          __builtin_amdgcn_s_setprio(1);
#pragma unroll
          for (int db = 0; db < 2; ++db) {
            Oa[q2][db] = __builtin_amdgcn_mfma_f32_32x32x16_bf16(vf[db][0], pb0, Oa[q2][db], 0, 0, 0);
            Oa[q2][db] = __builtin_amdgcn_mfma_f32_32x32x16_bf16(vf[db][1], pb1, Oa[q2][db], 0, 0, 0);
          }
          __builtin_amdgcn_s_setprio(0);
        }
      }
    }
  }

#pragma unroll
  for (int q2 = 0; q2 < 2; ++q2) {
    float v = lp[q2];
    v += __shfl_xor(v, 32);
    float rinv = 1.0f / v;
    const size_t rb = (size_t)(qrow0 + q2 * 32 + l31) * 1024 + h * 64;
#pragma unroll
    for (int db = 0; db < 2; ++db)
#pragma unroll
      for (int pr = 0; pr < 8; ++pr) {
        int reg = 2 * pr;
        int d0  = (reg & 3) + 8 * (reg >> 2) + 4 * g32 + db * 32;
        u32 pk = pkbf(Oa[q2][db][reg] * rinv, Oa[q2][db][reg + 1] * rinv);
        *(u32*)(ob + rb + d0) = pk;
      }
  }
}

// ---------------- host ----------------
extern "C" void kernel_launch(void* const* d_in, const int* in_sizes, int n_in,
                              void* d_out, int out_size, void* d_ws, size_t ws_size,
                              hipStream_t stream) {
  const float* x  = (const float*)d_in[0];
  const float* Wk = (const float*)d_in[1];
  const float* Wq = (const float*)d_in[2];
  const float* Wv = (const float*)d_in[3];
  const float* Wp = (const float*)d_in[4];
  const float* bp = (const float*)d_in[5];
  float* out = (float*)d_out;

  const size_t MC = (size_t)8192 * 1024;
  u16* xb  = (u16*)d_ws;
  u16* qb  = xb + MC;
  u16* kb2 = qb + MC;
  u16* vtb = kb2 + MC;
  u16* wqb = vtb + MC;   // 4 weight buffers contiguous: wq, wk, wv, wp
  u16* wpb = wqb + (size_t)3 * 1024 * 1024;
  u16* ob  = xb;  // xb dead after QKV GEMM; reuse for attention output

  cast5_bf16<<<dim3(512, 5), 256, 0, stream>>>(x, Wq, Wk, Wv, Wp, xb, wqb);

  const float qscale = 0.125f * 1.44269504088896340736f;  // 1/sqrt(D) * log2(e)
  gemm_qkv<<<1536, 256, 0, stream>>>(xb, wqb, qb, kb2, vtb, qscale);

  attn_fused<<<dim3(64, 8), 256, 0, stream>>>(qb, kb2, vtb, ob);

  gemm_out<<<512, 256, 0, stream>>>(ob, wpb, out, bp);
}

// Round 20
// 168.217 us; speedup vs baseline: 1.8051x; 1.8051x over previous
//
#include <hip/hip_runtime.h>
#include <stdint.h>

typedef __bf16 bf16_t;
typedef bf16_t bf16x2 __attribute__((ext_vector_type(2)));
typedef bf16_t bf16x8 __attribute__((ext_vector_type(8)));
typedef float f32x4 __attribute__((ext_vector_type(4)));
typedef float f32x16 __attribute__((ext_vector_type(16)));
typedef unsigned short u16;
typedef u16 u16x8 __attribute__((ext_vector_type(8)));
typedef u16 u16x4 __attribute__((ext_vector_type(4)));
typedef unsigned int u32;
typedef u32 u32x2 __attribute__((ext_vector_type(2)));
typedef u32 u32x4v __attribute__((ext_vector_type(4)));

// f32 -> bf16 RTNE (inputs finite; NaN path not needed)
__device__ __forceinline__ u16 f2b(float f) {
  uint32_t u = __builtin_bit_cast(uint32_t, f);
  u += 0x7fffu + ((u >> 16) & 1u);
  return (u16)(u >> 16);
}

// pack two f32 -> one u32 of 2 bf16 via compiler casts (no inline asm)
__device__ __forceinline__ u32 pkbf(float lo, float hi) {
  bf16x2 t = {(__bf16)lo, (__bf16)hi};
  return __builtin_bit_cast(u32, t);
}

__device__ __forceinline__ void gl_lds16(const void* g, void* l) {
  __builtin_amdgcn_global_load_lds(
      (const __attribute__((address_space(1))) uint32_t*)(uintptr_t)g,
      (__attribute__((address_space(3))) uint32_t*)(uintptr_t)l, 16, 0, 0);
}

// ---------------- fused cast: x + 4 weight matrices in ONE launch ----------------
__global__ void cast5_bf16(const float* __restrict__ x, const float* __restrict__ a,
                           const float* __restrict__ b, const float* __restrict__ c,
                           const float* __restrict__ d,
                           u16* __restrict__ xb, u16* __restrict__ wb) {
  const int y = blockIdx.y;
  const float* srcs[5] = {x, a, b, c, d};
  const float* src = srcs[y];
  u16* dp = (y == 0) ? xb : wb + (size_t)(y - 1) * 1024 * 1024;
  const int n8 = (y == 0) ? 1048576 : 131072;
  int i = blockIdx.x * blockDim.x + threadIdx.x;
  int stride = gridDim.x * blockDim.x;
  for (; i < n8; i += stride) {
    float4 p = ((const float4*)src)[2 * i];
    float4 q = ((const float4*)src)[2 * i + 1];
    u16x8 o;
    o[0] = f2b(p.x); o[1] = f2b(p.y); o[2] = f2b(p.z); o[3] = f2b(p.w);
    o[4] = f2b(q.x); o[5] = f2b(q.y); o[6] = f2b(q.z); o[7] = f2b(q.w);
    ((u16x8*)dp)[i] = o;
  }
}

// ---------------- merged QKV GEMM, BK=64, XOR-swizzled LDS, XCD 1D grid -----------
__global__ __launch_bounds__(256, 2)
void gemm_qkv(const u16* __restrict__ A, const u16* __restrict__ W3,
              u16* __restrict__ qb, u16* __restrict__ kb2, u16* __restrict__ vtb,
              float qscale) {
  __shared__ u16 As[128 * 64];
  __shared__ u16 Bs[128 * 64];
  const int tid  = threadIdx.x;
  const int lane = tid & 63;
  const int w    = tid >> 6;
  const int wm   = w >> 1, wn = w & 1;
  const int g    = lane >> 4, c = lane & 15;
  const int id   = blockIdx.x;
  const int wg   = (id & 7) * 192 + (id >> 3);   // XCD-contiguous remap (1536%8==0)
  const int which = wg >> 9;
  const int rem   = wg & 511;
  const int n0    = (rem & 7) * 128;
  const int m0    = (rem >> 3) * 128;
  const u16* Wt = W3 + (size_t)which * 1024 * 1024;

  f32x4 acc[4][4] = {};

  const int srow = tid >> 3;
  const int sslx = (tid & 7) ^ (srow & 7);
  const u16* gA = A  + (size_t)(m0 + srow) * 1024 + sslx * 8;
  const u16* gB = Wt + (size_t)(n0 + srow) * 1024 + sslx * 8;
  char* lA = (char*)As + w * 1024;
  char* lB = (char*)Bs + w * 1024;
  const int cx = c & 7;                 // read-side xor (row&7 == c&7)

#pragma unroll 1
  for (int kt = 0; kt < 1024; kt += 64) {
    __syncthreads();
#pragma unroll
    for (int j = 0; j < 4; ++j) {
      gl_lds16(gA + kt + (size_t)j * 32 * 1024, lA + j * 4096);
      gl_lds16(gB + kt + (size_t)j * 32 * 1024, lB + j * 4096);
    }
    __syncthreads();
#pragma unroll
    for (int ks = 0; ks < 2; ++ks) {
      bf16x8 af[4], bfr[4];
#pragma unroll
      for (int mi = 0; mi < 4; ++mi)
        af[mi] = *(const bf16x8*)((const char*)As + (wm * 64 + mi * 16 + c) * 128 +
                                  (((ks * 4 + g) ^ cx) << 4));
#pragma unroll
      for (int ni = 0; ni < 4; ++ni)
        bfr[ni] = *(const bf16x8*)((const char*)Bs + (wn * 64 + ni * 16 + c) * 128 +
                                   (((ks * 4 + g) ^ cx) << 4));
#pragma unroll
      for (int mi = 0; mi < 4; ++mi)
#pragma unroll
        for (int ni = 0; ni < 4; ++ni)
          acc[mi][ni] = __builtin_amdgcn_mfma_f32_16x16x32_bf16(af[mi], bfr[ni], acc[mi][ni], 0, 0, 0);
    }
  }

  const int rowb = m0 + wm * 64;
  const int colb = n0 + wn * 64;

  if (which <= 1) {
    u16* outb = (which == 0) ? qb : kb2;
    const float scale = (which == 0) ? qscale : 1.0f;
#pragma unroll
    for (int mi = 0; mi < 4; ++mi)
#pragma unroll
      for (int ni = 0; ni < 4; ++ni) {
        size_t base = (size_t)(rowb + mi * 16 + g * 4) * 1024 + (colb + ni * 16 + c);
#pragma unroll
        for (int r = 0; r < 4; ++r)
          outb[base + (size_t)r * 1024] = f2b(acc[mi][ni][r] * scale);
      }
  } else {
#pragma unroll
    for (int mi = 0; mi < 4; ++mi) {
      int row = rowb + mi * 16 + g * 4;
      int bb = row >> 11, tl = row & 2047;
#pragma unroll
      for (int ni = 0; ni < 4; ++ni) {
        int col = colb + ni * 16 + c;
        u16x4 pk;
#pragma unroll
        for (int r = 0; r < 4; ++r) pk[r] = f2b(acc[mi][ni][r]);
        *(u16x4*)(vtb + ((size_t)(bb * 1024 + col)) * 2048 + tl) = pk;
      }
    }
  }
}

// ---------------- output-projection GEMM, BK=64, swizzled: f32 out + bias ---------
__global__ __launch_bounds__(256, 2)
void gemm_out(const u16* __restrict__ A, const u16* __restrict__ Wt,
              float* __restrict__ outf, const float* __restrict__ bias) {
  __shared__ u16 As[128 * 64];
  __shared__ u16 Bs[128 * 64];
  const int tid  = threadIdx.x;
  const int lane = tid & 63;
  const int w    = tid >> 6;
  const int wm   = w >> 1, wn = w & 1;
  const int g    = lane >> 4, c = lane & 15;
  const int id   = blockIdx.x;
  const int wg   = (id & 7) * 64 + (id >> 3);    // 512 blocks, XCD-contiguous
  const int n0   = (wg & 7) * 128;
  const int m0   = (wg >> 3) * 128;

  f32x4 acc[4][4] = {};

  const int srow = tid >> 3;
  const int sslx = (tid & 7) ^ (srow & 7);
  const u16* gA = A  + (size_t)(m0 + srow) * 1024 + sslx * 8;
  const u16* gB = Wt + (size_t)(n0 + srow) * 1024 + sslx * 8;
  char* lA = (char*)As + w * 1024;
  char* lB = (char*)Bs + w * 1024;
  const int cx = c & 7;

#pragma unroll 1
  for (int kt = 0; kt < 1024; kt += 64) {
    __syncthreads();
#pragma unroll
    for (int j = 0; j < 4; ++j) {
      gl_lds16(gA + kt + (size_t)j * 32 * 1024, lA + j * 4096);
      gl_lds16(gB + kt + (size_t)j * 32 * 1024, lB + j * 4096);
    }
    __syncthreads();
#pragma unroll
    for (int ks = 0; ks < 2; ++ks) {
      bf16x8 af[4], bfr[4];
#pragma unroll
      for (int mi = 0; mi < 4; ++mi)
        af[mi] = *(const bf16x8*)((const char*)As + (wm * 64 + mi * 16 + c) * 128 +
                                  (((ks * 4 + g) ^ cx) << 4));
#pragma unroll
      for (int ni = 0; ni < 4; ++ni)
        bfr[ni] = *(const bf16x8*)((const char*)Bs + (wn * 64 + ni * 16 + c) * 128 +
                                   (((ks * 4 + g) ^ cx) << 4));
#pragma unroll
      for (int mi = 0; mi < 4; ++mi)
#pragma unroll
        for (int ni = 0; ni < 4; ++ni)
          acc[mi][ni] = __builtin_amdgcn_mfma_f32_16x16x32_bf16(af[mi], bfr[ni], acc[mi][ni], 0, 0, 0);
    }
  }

  const int rowb = m0 + wm * 64;
  const int colb = n0 + wn * 64;
#pragma unroll
  for (int ni = 0; ni < 4; ++ni) {
    int col = colb + ni * 16 + c;
    float bv = bias[col];
#pragma unroll
    for (int mi = 0; mi < 4; ++mi) {
      size_t base = (size_t)(rowb + mi * 16 + g * 4) * 1024 + col;
#pragma unroll
      for (int r = 0; r < 4; ++r)
        outf[base + (size_t)r * 1024] = acc[mi][ni][r] + bv;
    }
  }
}

// ---------------- fused attention v14 (R18 champion, 81us) -------------------------
// 32x32 swapped-QK, in-register softmax (exp2, log2e folded into Q GEMM scale),
// P^T via cvt_pk casts + permlane32_swap, O^T = mfma(V^T, P^T). gl_lds-direct
// staging (pre-swizzled source slot, linear dest), 64-key step, 2 barriers.
// Body size is at the 128-VGPR register budget: v13/v15 (128-key bodies) both
// spilled; this is the largest non-spilling shape.
__global__ __launch_bounds__(256, 2)
void attn_fused(const u16* __restrict__ qb, const u16* __restrict__ kb,
                const u16* __restrict__ vt, u16* __restrict__ ob) {
  __shared__ u16 KV[2][4096];  // [0]=K (row=k, col=d), [1]=V^T (row=d, col=k); swizzled

  const int bh = blockIdx.x;            // 0..63
  const int qt = blockIdx.y;            // 0..7
  const int b  = bh >> 4, h = bh & 15;
  const int tid  = threadIdx.x;
  const int lane = tid & 63;
  const int w    = tid >> 6;
  const int l31  = lane & 31, g32 = lane >> 5;

  // ---- staging: row r = tid>>3 (and r+32), slot pre-swizzled (tid&7)^(r&7) ----
  const int r  = tid >> 3;
  const int sx = (tid & 7) ^ (r & 7);
  const u16* kgs = kb + (size_t)(b * 2048 + r) * 1024 + h * 64 + sx * 8;
  const u16* vgs = vt + (size_t)(bh * 64 + r) * 2048 + sx * 8;
  char* lK = (char*)&KV[0][0] + w * 1024;   // wave-uniform dest; lane stride 16B
  char* lV = (char*)&KV[1][0] + w * 1024;

  const int qrow0 = b * 2048 + qt * 256 + w * 64;
  bf16x8 qf[2][4];
#pragma unroll
  for (int q2 = 0; q2 < 2; ++q2)
#pragma unroll
    for (int dc = 0; dc < 4; ++dc)
      qf[q2][dc] = *(const bf16x8*)(qb + (size_t)(qrow0 + q2 * 32 + l31) * 1024 +
                                    h * 64 + dc * 16 + g32 * 8);

  f32x16 Oa[2][2] = {};   // [q2][db] : O^T accumulators
  float lp[2] = {0.f, 0.f};

  const int xorv = (l31 & 7) << 4;      // read-side swizzle (row&7)<<4
  const int rowb = l31 * 128;           // row byte offset within 32-row half

#pragma unroll 1
  for (int step = 0; step < 32; ++step) {
    const int s0 = step * 64;
    __syncthreads();                 // A: all waves done READING prev tile (WAR)
    gl_lds16(kgs + (size_t)s0 * 1024,        lK);
    gl_lds16(kgs + (size_t)(s0 + 32) * 1024, lK + 4096);
    gl_lds16(vgs + s0,                       lV);
    gl_lds16(vgs + s0 + (size_t)32 * 2048,   lV + 4096);
    __syncthreads();                 // B: drains gl_lds (vmcnt 0) + all waves staged

    const char* kt  = (const char*)&KV[0][0];
    const char* vtl = (const char*)&KV[1][0];

#pragma unroll
    for (int kb2 = 0; kb2 < 2; ++kb2) {
      bf16x8 kf[4];
#pragma unroll
      for (int dc = 0; dc < 4; ++dc)
        kf[dc] = *(const bf16x8*)(kt + kb2 * 4096 + rowb + ((dc * 32 + g32 * 16) ^ xorv));
      bf16x8 vf[2][2];
#pragma unroll
      for (int db = 0; db < 2; ++db)
#pragma unroll
        for (int ck = 0; ck < 2; ++ck)
          vf[db][ck] = *(const bf16x8*)(vtl + db * 4096 + rowb +
                                        (((kb2 * 2 + ck) * 32 + g32 * 16) ^ xorv));

#pragma unroll
      for (int q2 = 0; q2 < 2; ++q2) {
        f32x16 S = {};
#pragma unroll
        for (int dc = 0; dc < 4; ++dc)
          S = __builtin_amdgcn_mfma_f32_32x32x16_bf16(kf[dc], qf[q2][dc], S, 0, 0, 0);

        float p[16];
#pragma unroll
        for (int rr = 0; rr < 16; ++rr) p[rr] = __builtin_amdgcn_exp2f(S[rr]);
        float s01 = (p[0] + p[1]) + (p[2] + p[3]);
        float s02 = (p[4] + p[5]) + (p[6] + p[7]);
        float s03 = (p[8] + p[9]) + (p[10] + p[11]);
        float s04 = (p[12] + p[13]) + (p[14] + p[15]);
        lp[q2] += (s01 + s02) + (s03 + s04);

        u32 w0 = pkbf(p[0], p[1]),   w1 = pkbf(p[2], p[3]);
        u32 w2 = pkbf(p[4], p[5]),   w3 = pkbf(p[6], p[7]);
        u32 w4 = pkbf(p[8], p[9]),   w5 = pkbf(p[10], p[11]);
        u32 w6 = pkbf(p[12], p[13]), w7 = pkbf(p[14], p[15]);
        u32x2 sA = __builtin_amdgcn_permlane32_swap(w0, w2, false, false);
        u32x2 sB = __builtin_amdgcn_permlane32_swap(w1, w3, false, false);
        u32x2 sC = __builtin_amdgcn_permlane32_swap(w4, w6, false, false);
        u32x2 sD = __builtin_amdgcn_permlane32_swap(w5, w7, false, false);
        u32x4v q0 = {sA[0], sB[0], sA[1], sB[1]};
        u32x4v q1 = {sC[0], sD[0], sC[1], sD[1]};
        bf16x8 pb0 = __builtin_bit_cast(bf16x8, q0);
        bf16x8 pb1 = __builtin_bit_cast(bf16x8, q1);

#pragma unroll
        for (int db = 0; db < 2; ++db) {
          Oa[q2][db] = __builtin_amdgcn_mfma_f32_32x32x16_bf16(vf[db][0], pb0, Oa[q2][db], 0, 0, 0);
          Oa[q2][db] = __builtin_amdgcn_mfma_f32_32x32x16_bf16(vf[db][1], pb1, Oa[q2][db], 0, 0, 0);
        }
      }
    }
  }

#pragma unroll
  for (int q2 = 0; q2 < 2; ++q2) {
    float v = lp[q2];
    v += __shfl_xor(v, 32);
    float rinv = 1.0f / v;
    const size_t rb = (size_t)(qrow0 + q2 * 32 + l31) * 1024 + h * 64;
#pragma unroll
    for (int db = 0; db < 2; ++db)
#pragma unroll
      for (int pr = 0; pr < 8; ++pr) {
        int reg = 2 * pr;
        int d0  = (reg & 3) + 8 * (reg >> 2) + 4 * g32 + db * 32;
        u32 pk = pkbf(Oa[q2][db][reg] * rinv, Oa[q2][db][reg + 1] * rinv);
        *(u32*)(ob + rb + d0) = pk;
      }
  }
}

// ---------------- host ----------------
extern "C" void kernel_launch(void* const* d_in, const int* in_sizes, int n_in,
                              void* d_out, int out_size, void* d_ws, size_t ws_size,
                              hipStream_t stream) {
  const float* x  = (const float*)d_in[0];
  const float* Wk = (const float*)d_in[1];
  const float* Wq = (const float*)d_in[2];
  const float* Wv = (const float*)d_in[3];
  const float* Wp = (const float*)d_in[4];
  const float* bp = (const float*)d_in[5];
  float* out = (float*)d_out;

  const size_t MC = (size_t)8192 * 1024;
  u16* xb  = (u16*)d_ws;
  u16* qb  = xb + MC;
  u16* kb2 = qb + MC;
  u16* vtb = kb2 + MC;
  u16* wqb = vtb + MC;   // 4 weight buffers contiguous: wq, wk, wv, wp
  u16* wpb = wqb + (size_t)3 * 1024 * 1024;
  u16* ob  = xb;  // xb dead after QKV GEMM; reuse for attention output

  cast5_bf16<<<dim3(512, 5), 256, 0, stream>>>(x, Wq, Wk, Wv, Wp, xb, wqb);

  const float qscale = 0.125f * 1.44269504088896340736f;  // 1/sqrt(D) * log2(e)
  gemm_qkv<<<1536, 256, 0, stream>>>(xb, wqb, qb, kb2, vtb, qscale);

  attn_fused<<<dim3(64, 8), 256, 0, stream>>>(qb, kb2, vtb, ob);

  gemm_out<<<512, 256, 0, stream>>>(ob, wpb, out, bp);
}